// Round 2
// baseline (3923.375 us; speedup 1.0000x reference)
//
#include <hip/hip_runtime.h>
#include <math.h>

#define TOTAL  65536      // B*2*N nodes
#define NDIM   128        // D
#define NEDGE  524288     // E
#define EDIM   64         // ED

// ---------------------------------------------------------------------------
// proj: P1 = ns @ W1a (msg_w1 rows 0..127), P2 = ns @ W1b (rows 128..255)
// block = 256 threads: t>>7 selects matrix, t&127 selects output neuron.
// ---------------------------------------------------------------------------
#define PROJ_RPB 8
__global__ __launch_bounds__(256) void proj_kernel(
    const float* __restrict__ ns, const float* __restrict__ msg_w1,
    float* __restrict__ P1, float* __restrict__ P2)
{
    __shared__ float s_x[PROJ_RPB][NDIM];
    const int t = threadIdx.x;
    const int m = t >> 7;
    const int j = t & 127;
    const size_t r0 = (size_t)blockIdx.x * PROJ_RPB;

    for (int k = t; k < PROJ_RPB * NDIM; k += 256)
        ((float*)s_x)[k] = ns[r0 * NDIM + k];
    __syncthreads();

    const float* __restrict__ W = msg_w1 + (size_t)m * 128 * NDIM;
    float acc[PROJ_RPB];
#pragma unroll
    for (int r = 0; r < PROJ_RPB; ++r) acc[r] = 0.f;
    for (int i = 0; i < NDIM; i += 4) {
        const float w0 = W[(i + 0) * NDIM + j];
        const float w1 = W[(i + 1) * NDIM + j];
        const float w2 = W[(i + 2) * NDIM + j];
        const float w3 = W[(i + 3) * NDIM + j];
#pragma unroll
        for (int r = 0; r < PROJ_RPB; ++r) {
            const float4 x = *(const float4*)&s_x[r][i];
            acc[r] = fmaf(x.x, w0, acc[r]);
            acc[r] = fmaf(x.y, w1, acc[r]);
            acc[r] = fmaf(x.z, w2, acc[r]);
            acc[r] = fmaf(x.w, w3, acc[r]);
        }
    }
    float* __restrict__ out = m ? P2 : P1;
#pragma unroll
    for (int r = 0; r < PROJ_RPB; ++r)
        out[(r0 + r) * NDIM + j] = acc[r];
}

// ---------------------------------------------------------------------------
// edge: h1 = relu(P1[src] + P2[dst] + ef@W1c + b1); h2 = relu(h1@W2 + b2);
//       m = h2@W3 + b3; summed[src] += m; summed[dst] += m.
// block = 128 threads (one output neuron each), EPB edges per block.
// edge_vertices is int32 on device (JAX x64 disabled downcasts int64).
// ---------------------------------------------------------------------------
#define EPB 16
__global__ __launch_bounds__(128) void edge_kernel(
    const float* __restrict__ P1, const float* __restrict__ P2,
    const float* __restrict__ ef, const int* __restrict__ ev,
    const float* __restrict__ w1c, const float* __restrict__ b1,
    const float* __restrict__ w2, const float* __restrict__ b2,
    const float* __restrict__ w3, const float* __restrict__ b3,
    float* __restrict__ summed)
{
    __shared__ float s_ef[EPB][EDIM];
    __shared__ float s_h[EPB][NDIM];
    __shared__ int   s_src[EPB], s_dst[EPB];
    const int j = threadIdx.x;
    const size_t e0 = (size_t)blockIdx.x * EPB;

    if (j < EPB * 2) {
        const int v = ev[e0 * 2 + j];
        if (j & 1) s_dst[j >> 1] = v;
        else       s_src[j >> 1] = v;
    }
    for (int k = j; k < EPB * EDIM; k += 128)
        ((float*)s_ef)[k] = ef[e0 * EDIM + k];
    __syncthreads();

    float acc[EPB];
    const float bb1 = b1[j];
#pragma unroll
    for (int r = 0; r < EPB; ++r)
        acc[r] = P1[(size_t)s_src[r] * NDIM + j] + P2[(size_t)s_dst[r] * NDIM + j] + bb1;

    for (int i = 0; i < EDIM; i += 4) {
        const float w0 = w1c[(i + 0) * NDIM + j];
        const float w1 = w1c[(i + 1) * NDIM + j];
        const float wv2 = w1c[(i + 2) * NDIM + j];
        const float wv3 = w1c[(i + 3) * NDIM + j];
#pragma unroll
        for (int r = 0; r < EPB; ++r) {
            const float4 x = *(const float4*)&s_ef[r][i];
            acc[r] = fmaf(x.x, w0, acc[r]);
            acc[r] = fmaf(x.y, w1, acc[r]);
            acc[r] = fmaf(x.z, wv2, acc[r]);
            acc[r] = fmaf(x.w, wv3, acc[r]);
        }
    }
#pragma unroll
    for (int r = 0; r < EPB; ++r) s_h[r][j] = fmaxf(acc[r], 0.f);
    __syncthreads();

    const float bb2 = b2[j];
#pragma unroll
    for (int r = 0; r < EPB; ++r) acc[r] = bb2;
    for (int i = 0; i < NDIM; i += 4) {
        const float w0 = w2[(i + 0) * NDIM + j];
        const float w1 = w2[(i + 1) * NDIM + j];
        const float wv2 = w2[(i + 2) * NDIM + j];
        const float wv3 = w2[(i + 3) * NDIM + j];
#pragma unroll
        for (int r = 0; r < EPB; ++r) {
            const float4 x = *(const float4*)&s_h[r][i];
            acc[r] = fmaf(x.x, w0, acc[r]);
            acc[r] = fmaf(x.y, w1, acc[r]);
            acc[r] = fmaf(x.z, wv2, acc[r]);
            acc[r] = fmaf(x.w, wv3, acc[r]);
        }
    }
    __syncthreads();
#pragma unroll
    for (int r = 0; r < EPB; ++r) s_h[r][j] = fmaxf(acc[r], 0.f);
    __syncthreads();

    const float bb3 = b3[j];
#pragma unroll
    for (int r = 0; r < EPB; ++r) acc[r] = bb3;
    for (int i = 0; i < NDIM; i += 4) {
        const float w0 = w3[(i + 0) * NDIM + j];
        const float w1 = w3[(i + 1) * NDIM + j];
        const float wv2 = w3[(i + 2) * NDIM + j];
        const float wv3 = w3[(i + 3) * NDIM + j];
#pragma unroll
        for (int r = 0; r < EPB; ++r) {
            const float4 x = *(const float4*)&s_h[r][i];
            acc[r] = fmaf(x.x, w0, acc[r]);
            acc[r] = fmaf(x.y, w1, acc[r]);
            acc[r] = fmaf(x.z, wv2, acc[r]);
            acc[r] = fmaf(x.w, wv3, acc[r]);
        }
    }
#pragma unroll
    for (int r = 0; r < EPB; ++r) {
        atomicAdd(&summed[(size_t)s_src[r] * NDIM + j], acc[r]);
        atomicAdd(&summed[(size_t)s_dst[r] * NDIM + j], acc[r]);
    }
}

// ---------------------------------------------------------------------------
// upd: x = [ns, summed, ns - ns[partner]] (384); 3-layer MLP -> ns_out
// partner = node ^ 4096  (flips the t bit of ((b*2+t)*4096 + n))
// ---------------------------------------------------------------------------
#define NPB 8
__global__ __launch_bounds__(128) void upd_kernel(
    const float* __restrict__ ns, const float* __restrict__ summed,
    const float* __restrict__ u1, const float* __restrict__ ub1,
    const float* __restrict__ u2, const float* __restrict__ ub2,
    const float* __restrict__ u3, const float* __restrict__ ub3,
    float* __restrict__ ns_out)
{
    __shared__ float s_x[NPB][3 * NDIM];
    __shared__ float s_h[NPB][NDIM];
    const int j = threadIdx.x;
    const int n0 = blockIdx.x * NPB;

#pragma unroll
    for (int r = 0; r < NPB; ++r) {
        const int node = n0 + r;
        const int partner = node ^ 4096;
        const float self = ns[(size_t)node * NDIM + j];
        s_x[r][j]       = self;
        s_x[r][128 + j] = summed[(size_t)node * NDIM + j];
        s_x[r][256 + j] = self - ns[(size_t)partner * NDIM + j];
    }
    __syncthreads();

    float acc[NPB];
    const float bb1 = ub1[j];
#pragma unroll
    for (int r = 0; r < NPB; ++r) acc[r] = bb1;
    for (int i = 0; i < 3 * NDIM; i += 4) {
        const float w0 = u1[(i + 0) * NDIM + j];
        const float w1 = u1[(i + 1) * NDIM + j];
        const float wv2 = u1[(i + 2) * NDIM + j];
        const float wv3 = u1[(i + 3) * NDIM + j];
#pragma unroll
        for (int r = 0; r < NPB; ++r) {
            const float4 x = *(const float4*)&s_x[r][i];
            acc[r] = fmaf(x.x, w0, acc[r]);
            acc[r] = fmaf(x.y, w1, acc[r]);
            acc[r] = fmaf(x.z, wv2, acc[r]);
            acc[r] = fmaf(x.w, wv3, acc[r]);
        }
    }
#pragma unroll
    for (int r = 0; r < NPB; ++r) s_h[r][j] = fmaxf(acc[r], 0.f);
    __syncthreads();

    const float bb2 = ub2[j];
#pragma unroll
    for (int r = 0; r < NPB; ++r) acc[r] = bb2;
    for (int i = 0; i < NDIM; i += 4) {
        const float w0 = u2[(i + 0) * NDIM + j];
        const float w1 = u2[(i + 1) * NDIM + j];
        const float wv2 = u2[(i + 2) * NDIM + j];
        const float wv3 = u2[(i + 3) * NDIM + j];
#pragma unroll
        for (int r = 0; r < NPB; ++r) {
            const float4 x = *(const float4*)&s_h[r][i];
            acc[r] = fmaf(x.x, w0, acc[r]);
            acc[r] = fmaf(x.y, w1, acc[r]);
            acc[r] = fmaf(x.z, wv2, acc[r]);
            acc[r] = fmaf(x.w, wv3, acc[r]);
        }
    }
    __syncthreads();
#pragma unroll
    for (int r = 0; r < NPB; ++r) s_h[r][j] = fmaxf(acc[r], 0.f);
    __syncthreads();

    const float bb3 = ub3[j];
#pragma unroll
    for (int r = 0; r < NPB; ++r) acc[r] = bb3;
    for (int i = 0; i < NDIM; i += 4) {
        const float w0 = u3[(i + 0) * NDIM + j];
        const float w1 = u3[(i + 1) * NDIM + j];
        const float wv2 = u3[(i + 2) * NDIM + j];
        const float wv3 = u3[(i + 3) * NDIM + j];
#pragma unroll
        for (int r = 0; r < NPB; ++r) {
            const float4 x = *(const float4*)&s_h[r][i];
            acc[r] = fmaf(x.x, w0, acc[r]);
            acc[r] = fmaf(x.y, w1, acc[r]);
            acc[r] = fmaf(x.z, wv2, acc[r]);
            acc[r] = fmaf(x.w, wv3, acc[r]);
        }
    }
#pragma unroll
    for (int r = 0; r < NPB; ++r)
        ns_out[(size_t)(n0 + r) * NDIM + j] = acc[r];
}

// ---------------------------------------------------------------------------
// gate + per-graph-row reduction: gs[b*2+t][:] = sum_n ns*sigmoid(ns@gw+gb)
// ---------------------------------------------------------------------------
#define GPB 8
__global__ __launch_bounds__(128) void gate_kernel(
    const float* __restrict__ ns, const float* __restrict__ gw,
    const float* __restrict__ gb, float* __restrict__ gs)
{
    __shared__ float s_x[GPB][NDIM];
    const int j = threadIdx.x;
    const int n0 = blockIdx.x * GPB;
#pragma unroll
    for (int r = 0; r < GPB; ++r)
        s_x[r][j] = ns[(size_t)(n0 + r) * NDIM + j];
    __syncthreads();

    float acc[GPB];
    const float bb = gb[j];
#pragma unroll
    for (int r = 0; r < GPB; ++r) acc[r] = bb;
    for (int i = 0; i < NDIM; i += 4) {
        const float w0 = gw[(i + 0) * NDIM + j];
        const float w1 = gw[(i + 1) * NDIM + j];
        const float wv2 = gw[(i + 2) * NDIM + j];
        const float wv3 = gw[(i + 3) * NDIM + j];
#pragma unroll
        for (int r = 0; r < GPB; ++r) {
            const float4 x = *(const float4*)&s_x[r][i];
            acc[r] = fmaf(x.x, w0, acc[r]);
            acc[r] = fmaf(x.y, w1, acc[r]);
            acc[r] = fmaf(x.z, wv2, acc[r]);
            acc[r] = fmaf(x.w, wv3, acc[r]);
        }
    }
    float part = 0.f;
#pragma unroll
    for (int r = 0; r < GPB; ++r) {
        const float g = 1.f / (1.f + expf(-acc[r]));
        part += s_x[r][j] * g;
    }
    atomicAdd(&gs[(n0 >> 12) * NDIM + j], part);
}

// ---------------------------------------------------------------------------
// final: out = relu(gs @ agg_w1 + ab1) @ agg_w2 + ab2    (16x128 -> 16x128)
// ---------------------------------------------------------------------------
__global__ __launch_bounds__(256) void final_kernel(
    const float* __restrict__ gs,
    const float* __restrict__ aw1, const float* __restrict__ ab1,
    const float* __restrict__ aw2, const float* __restrict__ ab2,
    float* __restrict__ out)
{
    __shared__ float s_g[16 * 128];
    __shared__ float s_h[16 * 256];
    const int t = threadIdx.x;
    for (int k = t; k < 16 * 128; k += 256) s_g[k] = gs[k];
    __syncthreads();
    for (int r = 0; r < 16; ++r) {
        float a = ab1[t];
        for (int i = 0; i < 128; ++i)
            a = fmaf(s_g[r * 128 + i], aw1[i * 256 + t], a);
        s_h[r * 256 + t] = fmaxf(a, 0.f);
    }
    __syncthreads();
    for (int k = t; k < 16 * 128; k += 256) {
        const int r = k >> 7, j = k & 127;
        float a = ab2[j];
        for (int i = 0; i < 256; ++i)
            a = fmaf(s_h[r * 256 + i], aw2[i * 128 + j], a);
        out[k] = a;
    }
}

// ---------------------------------------------------------------------------
// Workspace aliasing (4 node-sized fp32 buffers, ~134 MB total):
//   L1: proj nf->(W0,W1); edge (W0,W1)->W2; upd (nf,W2)->W3
//   L2: proj W3->(W0,W1); edge (W0,W1)->W2; upd (W3,W2)->W0
//   L3: proj W0->(W1,W3); edge (W1,W3)->W2; upd (W0,W2)->W1
//   gate reads W1.
// ---------------------------------------------------------------------------
extern "C" void kernel_launch(void* const* d_in, const int* in_sizes, int n_in,
                              void* d_out, int out_size, void* d_ws, size_t ws_size,
                              hipStream_t stream)
{
    const float* nf      = (const float*)d_in[0];
    const float* ef      = (const float*)d_in[1];
    const int*   ev      = (const int*)d_in[2];   // int32 on device!
    const float* msg_w1  = (const float*)d_in[3];
    const float* msg_b1  = (const float*)d_in[4];
    const float* msg_w2  = (const float*)d_in[5];
    const float* msg_b2  = (const float*)d_in[6];
    const float* msg_w3  = (const float*)d_in[7];
    const float* msg_b3  = (const float*)d_in[8];
    const float* upd_w1  = (const float*)d_in[9];
    const float* upd_b1  = (const float*)d_in[10];
    const float* upd_w2  = (const float*)d_in[11];
    const float* upd_b2  = (const float*)d_in[12];
    const float* upd_w3  = (const float*)d_in[13];
    const float* upd_b3  = (const float*)d_in[14];
    const float* gate_w  = (const float*)d_in[15];
    const float* gate_b  = (const float*)d_in[16];
    const float* agg_w1  = (const float*)d_in[17];
    const float* agg_b1  = (const float*)d_in[18];
    const float* agg_w2  = (const float*)d_in[19];
    const float* agg_b2  = (const float*)d_in[20];

    const size_t NS = (size_t)TOTAL * NDIM;   // floats per node-state buffer
    float* W0 = (float*)d_ws;
    float* W1 = W0 + NS;
    float* W2 = W1 + NS;
    float* W3 = W2 + NS;
    float* gs = W3 + NS;

    const float* w1c = msg_w1 + 256 * NDIM;

    // per-layer buffer assignment per the aliasing plan above
    const float* curs[3] = { nf, W3, W0 };
    float* p1s[3]  = { W0, W0, W1 };
    float* p2s[3]  = { W1, W1, W3 };
    float* nxts[3] = { W3, W0, W1 };
    float* summed  = W2;

    for (int l = 0; l < 3; ++l) {
        proj_kernel<<<TOTAL / PROJ_RPB, 256, 0, stream>>>(curs[l], msg_w1, p1s[l], p2s[l]);
        hipMemsetAsync(summed, 0, NS * sizeof(float), stream);
        edge_kernel<<<NEDGE / EPB, 128, 0, stream>>>(p1s[l], p2s[l], ef, ev,
            w1c, msg_b1, msg_w2, msg_b2, msg_w3, msg_b3, summed);
        upd_kernel<<<TOTAL / NPB, 128, 0, stream>>>(curs[l], summed,
            upd_w1, upd_b1, upd_w2, upd_b2, upd_w3, upd_b3, nxts[l]);
    }
    hipMemsetAsync(gs, 0, (size_t)16 * NDIM * sizeof(float), stream);
    gate_kernel<<<TOTAL / GPB, 128, 0, stream>>>(W1, gate_w, gate_b, gs);
    final_kernel<<<1, 256, 0, stream>>>(gs, agg_w1, agg_b1, agg_w2, agg_b2,
                                        (float*)d_out);
}

// Round 3
// 2300.085 us; speedup vs baseline: 1.7058x; 1.7058x over previous
//
#include <hip/hip_runtime.h>
#include <math.h>

#define TOTAL  65536      // B*2*N nodes
#define NDIM   128        // D
#define NEDGE  524288     // E
#define EDIM   64         // ED

typedef __bf16 bf16x8 __attribute__((ext_vector_type(8)));
typedef float  f32x4  __attribute__((ext_vector_type(4)));
typedef unsigned int u32x4 __attribute__((ext_vector_type(4)));

#define MFMA(a, b, c) __builtin_amdgcn_mfma_f32_16x16x32_bf16((a), (b), (c), 0, 0, 0)

static __device__ __forceinline__ float b2f(unsigned short u) {
    union { float f; unsigned int i; } v; v.i = ((unsigned int)u) << 16; return v.f;
}
static __device__ __forceinline__ unsigned short f2b(float f) {  // RNE
    union { float f; unsigned int i; } v; v.f = f;
    unsigned int r = v.i + 0x7FFFu + ((v.i >> 16) & 1u);
    return (unsigned short)(r >> 16);
}
static __device__ __forceinline__ bf16x8 ldfrag(const unsigned short* p) {
    return __builtin_bit_cast(bf16x8, *(const u32x4*)p);
}

// ---------------------------------------------------------------------------
// cvt: fp32 -> bf16, vectorized
// ---------------------------------------------------------------------------
__global__ __launch_bounds__(256) void cvt_kernel(
    const float* __restrict__ in, unsigned short* __restrict__ out, int n4)
{
    int i = blockIdx.x * 256 + threadIdx.x;
    if (i < n4) {
        float4 x = *(const float4*)&in[(size_t)i * 4];
        out[(size_t)i * 4 + 0] = f2b(x.x);
        out[(size_t)i * 4 + 1] = f2b(x.y);
        out[(size_t)i * 4 + 2] = f2b(x.z);
        out[(size_t)i * 4 + 3] = f2b(x.w);
    }
}

// transpose fp32 [K][N] -> bf16 [N][K]
__global__ __launch_bounds__(256) void tk_kernel(
    const float* __restrict__ src, unsigned short* __restrict__ dst, int K, int N)
{
    int idx = blockIdx.x * 256 + threadIdx.x;
    if (idx < N * K) {
        int n = idx / K, k = idx - n * K;
        dst[idx] = f2b(src[(size_t)k * N + n]);
    }
}

// ---------------------------------------------------------------------------
// proj (MFMA): [P1|P2] = ns @ [W1a|W1b].  Block = 64 nodes, 4 waves.
// Wave w: 16 nodes (rows), 16 col-fragments (256 outputs).
// ---------------------------------------------------------------------------
__global__ __launch_bounds__(256) void proj_mfma(
    const unsigned short* __restrict__ ns, const unsigned short* __restrict__ w1abT,
    unsigned short* __restrict__ P1, unsigned short* __restrict__ P2)
{
    const int tid = threadIdx.x;
    const int w = tid >> 6, l = tid & 63;
    const int lr = l & 15, lg = l >> 4;
    const size_t n0 = (size_t)blockIdx.x * 64 + w * 16;

    bf16x8 af[4];
#pragma unroll
    for (int kb = 0; kb < 4; ++kb)
        af[kb] = ldfrag(&ns[(n0 + lr) * NDIM + kb * 32 + lg * 8]);

    f32x4 acc[16];
#pragma unroll
    for (int nb = 0; nb < 16; ++nb) {
        acc[nb] = (f32x4){0.f, 0.f, 0.f, 0.f};
#pragma unroll
        for (int kb = 0; kb < 4; ++kb)
            acc[nb] = MFMA(af[kb], ldfrag(&w1abT[(size_t)(nb * 16 + lr) * 128 + kb * 32 + lg * 8]), acc[nb]);
    }
#pragma unroll
    for (int nb = 0; nb < 16; ++nb) {
        const int col = nb * 16 + lr;
        unsigned short* out = (col < 128) ? P1 : P2;
        const int c = col & 127;
#pragma unroll
        for (int r = 0; r < 4; ++r)
            out[(n0 + lg * 4 + r) * NDIM + c] = f2b(acc[nb][r]);
    }
}

// ---------------------------------------------------------------------------
// edge (MFMA): block = 64 edges, 4 waves; wave w owns edges w*16..w*16+15.
// L1: acc = P1[src]+P2[dst]+b1 (fp32 LDS) + ef@W1c ; relu -> s_h0 (bf16 swz)
// L2: s_h0 @ W2 + b2 ; relu -> s_h1 ; L3: s_h1 @ W3 + b3 -> s_c ; scatter.
// ---------------------------------------------------------------------------
__global__ __launch_bounds__(256) void edge_mfma(
    const unsigned short* __restrict__ P1, const unsigned short* __restrict__ P2,
    const float* __restrict__ ef, const int* __restrict__ ev,
    const unsigned short* __restrict__ w1cT, const unsigned short* __restrict__ w2T,
    const unsigned short* __restrict__ w3T,
    const float* __restrict__ b1, const float* __restrict__ b2,
    const float* __restrict__ b3, float* __restrict__ summed)
{
    __shared__ float s_c[64 * 128];            // 32 KB: P-sums, then messages
    __shared__ unsigned short s_h0[64 * 128];  // 16 KB
    __shared__ unsigned short s_h1[64 * 128];  // 16 KB
    __shared__ int s_src[64], s_dst[64];

    const int tid = threadIdx.x;
    const int w = tid >> 6, l = tid & 63;
    const int lr = l & 15, lg = l >> 4;
    const size_t eblk = (size_t)blockIdx.x * 64;

    if (tid < 128) {
        const int v = ev[eblk * 2 + tid];
        if (tid & 1) s_dst[tid >> 1] = v; else s_src[tid >> 1] = v;
    }
    __syncthreads();

    for (int k = tid; k < 64 * 128; k += 256) {
        const int row = k >> 7, col = k & 127;
        s_c[k] = b2f(P1[(size_t)s_src[row] * NDIM + col]) +
                 b2f(P2[(size_t)s_dst[row] * NDIM + col]) + b1[col];
    }
    __syncthreads();

    // ---- Layer 1: K = 64 (edge features, cvt on the fly) ----
    const size_t erow = eblk + w * 16 + lr;
    bf16x8 af[4];
#pragma unroll
    for (int kb = 0; kb < 2; ++kb) {
        const float4 x0 = *(const float4*)&ef[erow * EDIM + kb * 32 + lg * 8];
        const float4 x1 = *(const float4*)&ef[erow * EDIM + kb * 32 + lg * 8 + 4];
        u32x4 u;
        u[0] = (unsigned int)f2b(x0.x) | ((unsigned int)f2b(x0.y) << 16);
        u[1] = (unsigned int)f2b(x0.z) | ((unsigned int)f2b(x0.w) << 16);
        u[2] = (unsigned int)f2b(x1.x) | ((unsigned int)f2b(x1.y) << 16);
        u[3] = (unsigned int)f2b(x1.z) | ((unsigned int)f2b(x1.w) << 16);
        af[kb] = __builtin_bit_cast(bf16x8, u);
    }

    f32x4 acc[8];
#pragma unroll
    for (int nb = 0; nb < 8; ++nb) {
#pragma unroll
        for (int r = 0; r < 4; ++r)
            acc[nb][r] = s_c[(w * 16 + lg * 4 + r) * 128 + nb * 16 + lr];
#pragma unroll
        for (int kb = 0; kb < 2; ++kb)
            acc[nb] = MFMA(af[kb], ldfrag(&w1cT[(size_t)(nb * 16 + lr) * EDIM + kb * 32 + lg * 8]), acc[nb]);
    }
#pragma unroll
    for (int nb = 0; nb < 8; ++nb)
#pragma unroll
        for (int r = 0; r < 4; ++r) {
            const int row = w * 16 + lg * 4 + r;
            const int us = (row * 128 + nb * 16 + lr) ^ ((row & 7) << 3);
            s_h0[us] = f2b(fmaxf(acc[nb][r], 0.f));
        }

    // ---- Layer 2: K = 128 ----
    {
        const int arow = w * 16 + lr;
#pragma unroll
        for (int kb = 0; kb < 4; ++kb)
            af[kb] = ldfrag(&s_h0[(arow * 128 + kb * 32 + lg * 8) ^ ((arow & 7) << 3)]);
    }
#pragma unroll
    for (int nb = 0; nb < 8; ++nb) {
        const float bv = b2[nb * 16 + lr];
        acc[nb] = (f32x4){bv, bv, bv, bv};
#pragma unroll
        for (int kb = 0; kb < 4; ++kb)
            acc[nb] = MFMA(af[kb], ldfrag(&w2T[(size_t)(nb * 16 + lr) * 128 + kb * 32 + lg * 8]), acc[nb]);
    }
#pragma unroll
    for (int nb = 0; nb < 8; ++nb)
#pragma unroll
        for (int r = 0; r < 4; ++r) {
            const int row = w * 16 + lg * 4 + r;
            const int us = (row * 128 + nb * 16 + lr) ^ ((row & 7) << 3);
            s_h1[us] = f2b(fmaxf(acc[nb][r], 0.f));
        }

    // ---- Layer 3: K = 128, no relu ----
    {
        const int arow = w * 16 + lr;
#pragma unroll
        for (int kb = 0; kb < 4; ++kb)
            af[kb] = ldfrag(&s_h1[(arow * 128 + kb * 32 + lg * 8) ^ ((arow & 7) << 3)]);
    }
#pragma unroll
    for (int nb = 0; nb < 8; ++nb) {
        const float bv = b3[nb * 16 + lr];
        acc[nb] = (f32x4){bv, bv, bv, bv};
#pragma unroll
        for (int kb = 0; kb < 4; ++kb)
            acc[nb] = MFMA(af[kb], ldfrag(&w3T[(size_t)(nb * 16 + lr) * 128 + kb * 32 + lg * 8]), acc[nb]);
#pragma unroll
        for (int r = 0; r < 4; ++r)
            s_c[(w * 16 + lg * 4 + r) * 128 + nb * 16 + lr] = acc[nb][r];
    }

    // ---- scatter (wave-private rows, coalesced atomics) ----
    for (int r = 0; r < 16; ++r) {
        const int e = w * 16 + r;
        const size_t s = (size_t)s_src[e] * NDIM, dd = (size_t)s_dst[e] * NDIM;
        const float v0 = s_c[e * 128 + l];
        const float v1 = s_c[e * 128 + 64 + l];
        atomicAdd(&summed[s + l], v0);
        atomicAdd(&summed[s + 64 + l], v1);
        atomicAdd(&summed[dd + l], v0);
        atomicAdd(&summed[dd + 64 + l], v1);
    }
}

// ---------------------------------------------------------------------------
// upd (MFMA): x = [ns, summed, ns - partner] (K=384); 3-layer MLP -> ns bf16
// Block = 64 nodes, 4 waves.
// ---------------------------------------------------------------------------
__global__ __launch_bounds__(256) void upd_mfma(
    const unsigned short* __restrict__ ns, const float* __restrict__ summed,
    const unsigned short* __restrict__ u1T, const unsigned short* __restrict__ u2T,
    const unsigned short* __restrict__ u3T,
    const float* __restrict__ ub1, const float* __restrict__ ub2,
    const float* __restrict__ ub3, unsigned short* __restrict__ out)
{
    __shared__ unsigned short s_a[64 * 384];   // 48 KB
    __shared__ unsigned short s_h0[64 * 128];  // 16 KB
    __shared__ unsigned short s_h1[64 * 128];  // 16 KB

    const int tid = threadIdx.x;
    const int w = tid >> 6, l = tid & 63;
    const int lr = l & 15, lg = l >> 4;
    const int n0blk = blockIdx.x * 64;

    for (int k = tid; k < 64 * 128; k += 256) {
        const int row = k >> 7, col = k & 127;
        const int node = n0blk + row, partner = node ^ 4096;
        const unsigned short sv = ns[(size_t)node * NDIM + col];
        const float att = b2f(sv) - b2f(ns[(size_t)partner * NDIM + col]);
        const float sm = summed[(size_t)node * NDIM + col];
        const int base = row * 384, sw = (row & 7) << 3;
        s_a[(base + col) ^ sw]       = sv;
        s_a[(base + 128 + col) ^ sw] = f2b(sm);
        s_a[(base + 256 + col) ^ sw] = f2b(att);
    }
    __syncthreads();

    // ---- Layer 1: K = 384 ----
    const int arow = w * 16 + lr;
    const int asw = (arow & 7) << 3;
    bf16x8 af[12];
#pragma unroll
    for (int kb = 0; kb < 12; ++kb)
        af[kb] = ldfrag(&s_a[(arow * 384 + kb * 32 + lg * 8) ^ asw]);

    f32x4 acc[8];
#pragma unroll
    for (int nb = 0; nb < 8; ++nb) {
        const float bv = ub1[nb * 16 + lr];
        acc[nb] = (f32x4){bv, bv, bv, bv};
#pragma unroll
        for (int kb = 0; kb < 12; ++kb)
            acc[nb] = MFMA(af[kb], ldfrag(&u1T[(size_t)(nb * 16 + lr) * 384 + kb * 32 + lg * 8]), acc[nb]);
    }
#pragma unroll
    for (int nb = 0; nb < 8; ++nb)
#pragma unroll
        for (int r = 0; r < 4; ++r) {
            const int row = w * 16 + lg * 4 + r;
            const int us = (row * 128 + nb * 16 + lr) ^ ((row & 7) << 3);
            s_h0[us] = f2b(fmaxf(acc[nb][r], 0.f));
        }

    // ---- Layer 2: K = 128 ----
#pragma unroll
    for (int kb = 0; kb < 4; ++kb)
        af[kb] = ldfrag(&s_h0[(arow * 128 + kb * 32 + lg * 8) ^ asw]);
#pragma unroll
    for (int nb = 0; nb < 8; ++nb) {
        const float bv = ub2[nb * 16 + lr];
        acc[nb] = (f32x4){bv, bv, bv, bv};
#pragma unroll
        for (int kb = 0; kb < 4; ++kb)
            acc[nb] = MFMA(af[kb], ldfrag(&u2T[(size_t)(nb * 16 + lr) * 128 + kb * 32 + lg * 8]), acc[nb]);
    }
#pragma unroll
    for (int nb = 0; nb < 8; ++nb)
#pragma unroll
        for (int r = 0; r < 4; ++r) {
            const int row = w * 16 + lg * 4 + r;
            const int us = (row * 128 + nb * 16 + lr) ^ ((row & 7) << 3);
            s_h1[us] = f2b(fmaxf(acc[nb][r], 0.f));
        }

    // ---- Layer 3: K = 128, no relu ----
#pragma unroll
    for (int kb = 0; kb < 4; ++kb)
        af[kb] = ldfrag(&s_h1[(arow * 128 + kb * 32 + lg * 8) ^ asw]);
#pragma unroll
    for (int nb = 0; nb < 8; ++nb) {
        const float bv = ub3[nb * 16 + lr];
        acc[nb] = (f32x4){bv, bv, bv, bv};
#pragma unroll
        for (int kb = 0; kb < 4; ++kb)
            acc[nb] = MFMA(af[kb], ldfrag(&u3T[(size_t)(nb * 16 + lr) * 128 + kb * 32 + lg * 8]), acc[nb]);
#pragma unroll
        for (int r = 0; r < 4; ++r)
            out[(size_t)(n0blk + w * 16 + lg * 4 + r) * NDIM + nb * 16 + lr] = f2b(acc[nb][r]);
    }
}

// ---------------------------------------------------------------------------
// gate + per-graph reduction (VALU, bf16 node states)
// ---------------------------------------------------------------------------
#define GPB 8
__global__ __launch_bounds__(128) void gate_kernel(
    const unsigned short* __restrict__ ns, const float* __restrict__ gw,
    const float* __restrict__ gb, float* __restrict__ gs)
{
    __shared__ float s_x[GPB][NDIM];
    const int j = threadIdx.x;
    const int n0 = blockIdx.x * GPB;
#pragma unroll
    for (int r = 0; r < GPB; ++r)
        s_x[r][j] = b2f(ns[(size_t)(n0 + r) * NDIM + j]);
    __syncthreads();

    float acc[GPB];
    const float bb = gb[j];
#pragma unroll
    for (int r = 0; r < GPB; ++r) acc[r] = bb;
    for (int i = 0; i < NDIM; i += 4) {
        const float w0 = gw[(i + 0) * NDIM + j];
        const float w1 = gw[(i + 1) * NDIM + j];
        const float wv2 = gw[(i + 2) * NDIM + j];
        const float wv3 = gw[(i + 3) * NDIM + j];
#pragma unroll
        for (int r = 0; r < GPB; ++r) {
            const float4 x = *(const float4*)&s_x[r][i];
            acc[r] = fmaf(x.x, w0, acc[r]);
            acc[r] = fmaf(x.y, w1, acc[r]);
            acc[r] = fmaf(x.z, wv2, acc[r]);
            acc[r] = fmaf(x.w, wv3, acc[r]);
        }
    }
    float part = 0.f;
#pragma unroll
    for (int r = 0; r < GPB; ++r) {
        const float g = 1.f / (1.f + expf(-acc[r]));
        part += s_x[r][j] * g;
    }
    atomicAdd(&gs[(n0 >> 12) * NDIM + j], part);
}

// ---------------------------------------------------------------------------
// final: out = relu(gs @ agg_w1 + ab1) @ agg_w2 + ab2    (16x128 -> 16x128)
// ---------------------------------------------------------------------------
__global__ __launch_bounds__(256) void final_kernel(
    const float* __restrict__ gs,
    const float* __restrict__ aw1, const float* __restrict__ ab1,
    const float* __restrict__ aw2, const float* __restrict__ ab2,
    float* __restrict__ out)
{
    __shared__ float s_g[16 * 128];
    __shared__ float s_h[16 * 256];
    const int t = threadIdx.x;
    for (int k = t; k < 16 * 128; k += 256) s_g[k] = gs[k];
    __syncthreads();
    for (int r = 0; r < 16; ++r) {
        float a = ab1[t];
        for (int i = 0; i < 128; ++i)
            a = fmaf(s_g[r * 128 + i], aw1[i * 256 + t], a);
        s_h[r * 256 + t] = fmaxf(a, 0.f);
    }
    __syncthreads();
    for (int k = t; k < 16 * 128; k += 256) {
        const int r = k >> 7, j = k & 127;
        float a = ab2[j];
        for (int i = 0; i < 256; ++i)
            a = fmaf(s_h[r * 256 + i], aw2[i * 128 + j], a);
        out[k] = a;
    }
}

// ---------------------------------------------------------------------------
extern "C" void kernel_launch(void* const* d_in, const int* in_sizes, int n_in,
                              void* d_out, int out_size, void* d_ws, size_t ws_size,
                              hipStream_t stream)
{
    const float* nf      = (const float*)d_in[0];
    const float* ef      = (const float*)d_in[1];
    const int*   ev      = (const int*)d_in[2];
    const float* msg_w1  = (const float*)d_in[3];
    const float* msg_b1  = (const float*)d_in[4];
    const float* msg_w2  = (const float*)d_in[5];
    const float* msg_b2  = (const float*)d_in[6];
    const float* msg_w3  = (const float*)d_in[7];
    const float* msg_b3  = (const float*)d_in[8];
    const float* upd_w1  = (const float*)d_in[9];
    const float* upd_b1  = (const float*)d_in[10];
    const float* upd_w2  = (const float*)d_in[11];
    const float* upd_b2  = (const float*)d_in[12];
    const float* upd_w3  = (const float*)d_in[13];
    const float* upd_b3  = (const float*)d_in[14];
    const float* gate_w  = (const float*)d_in[15];
    const float* gate_b  = (const float*)d_in[16];
    const float* agg_w1  = (const float*)d_in[17];
    const float* agg_b1  = (const float*)d_in[18];
    const float* agg_w2  = (const float*)d_in[19];
    const float* agg_b2  = (const float*)d_in[20];

    const size_t NS = (size_t)TOTAL * NDIM;   // elements per node-state tensor
    unsigned short* ns0 = (unsigned short*)d_ws;
    unsigned short* nsA = ns0 + NS;
    unsigned short* nsB = nsA + NS;
    unsigned short* P1  = nsB + NS;
    unsigned short* P2  = P1 + NS;
    float* summed = (float*)(P2 + NS);
    float* gs     = summed + NS;
    unsigned short* w1abT = (unsigned short*)(gs + 16 * NDIM);
    unsigned short* w1cT  = w1abT + 256 * 128;
    unsigned short* w2T   = w1cT + 128 * 64;
    unsigned short* w3T   = w2T + 128 * 128;
    unsigned short* u1T   = w3T + 128 * 128;
    unsigned short* u2T   = u1T + 128 * 384;
    unsigned short* u3T   = u2T + 128 * 128;

    // pre-convert: node features and transposed bf16 weights
    cvt_kernel<<<(int)(NS / 4 + 255) / 256, 256, 0, stream>>>(nf, ns0, (int)(NS / 4));
    tk_kernel<<<(128 * 128 + 255) / 256, 256, 0, stream>>>(msg_w1, w1abT, 128, 128);
    tk_kernel<<<(128 * 128 + 255) / 256, 256, 0, stream>>>(msg_w1 + 128 * 128, w1abT + 128 * 128, 128, 128);
    tk_kernel<<<(64 * 128 + 255) / 256, 256, 0, stream>>>(msg_w1 + 256 * 128, w1cT, 64, 128);
    tk_kernel<<<(128 * 128 + 255) / 256, 256, 0, stream>>>(msg_w2, w2T, 128, 128);
    tk_kernel<<<(128 * 128 + 255) / 256, 256, 0, stream>>>(msg_w3, w3T, 128, 128);
    tk_kernel<<<(384 * 128 + 255) / 256, 256, 0, stream>>>(upd_w1, u1T, 384, 128);
    tk_kernel<<<(128 * 128 + 255) / 256, 256, 0, stream>>>(upd_w2, u2T, 128, 128);
    tk_kernel<<<(128 * 128 + 255) / 256, 256, 0, stream>>>(upd_w3, u3T, 128, 128);

    const unsigned short* curs[3] = { ns0, nsA, nsB };
    unsigned short* nxts[3]       = { nsA, nsB, nsA };
    for (int lyr = 0; lyr < 3; ++lyr) {
        proj_mfma<<<TOTAL / 64, 256, 0, stream>>>(curs[lyr], w1abT, P1, P2);
        hipMemsetAsync(summed, 0, NS * sizeof(float), stream);
        edge_mfma<<<NEDGE / 64, 256, 0, stream>>>(P1, P2, ef, ev, w1cT, w2T, w3T,
                                                  msg_b1, msg_b2, msg_b3, summed);
        upd_mfma<<<TOTAL / 64, 256, 0, stream>>>(curs[lyr], summed, u1T, u2T, u3T,
                                                 upd_b1, upd_b2, upd_b3, nxts[lyr]);
    }
    hipMemsetAsync(gs, 0, (size_t)16 * NDIM * sizeof(float), stream);
    gate_kernel<<<TOTAL / GPB, 128, 0, stream>>>(nsA, gate_w, gate_b, gs);
    final_kernel<<<1, 256, 0, stream>>>(gs, agg_w1, agg_b1, agg_w2, agg_b2,
                                        (float*)d_out);
}